// Round 3
// baseline (400.615 us; speedup 1.0000x reference)
//
#include <hip/hip_runtime.h>
#include <hip/hip_fp16.h>

// Problem constants
#define NF 32
#define DM 256
#define HH 128
#define BB 16
#define TT 512
#define BT 8192            // B*T tokens
#define OUT_W_OFF 2097152  // B*T*D
#define EPS 1e-5f

typedef __bf16 bf16x8 __attribute__((ext_vector_type(8)));
typedef float  f32x16 __attribute__((ext_vector_type(16)));
typedef __fp16 f16x2 __attribute__((ext_vector_type(2)));
typedef __fp16 f16x8 __attribute__((ext_vector_type(8)));

__device__ __forceinline__ float eluf(float z){ return z > 0.f ? z : __expf(z) - 1.f; }
__device__ __forceinline__ float sigm(float z){ return 1.f/(1.f + __expf(-z)); }
__device__ __forceinline__ unsigned f2bf(float x){
  unsigned u = __float_as_uint(x);
  u += 0x7fffu + ((u>>16)&1u);   // RNE
  return u>>16;
}
__device__ __forceinline__ float rdlane(float v, int l){
  return __uint_as_float(__builtin_amdgcn_readlane(__float_as_uint(v), l));
}
// broadcast token-indexed value for MFMA C/D row r: m = (r&3)+8*(r>>2)+4*q
__device__ __forceinline__ float qsel(float v, int mb, int lane){
  float a0 = rdlane(v, mb), a1 = rdlane(v, mb+4);
  return (lane & 32) ? a1 : a0;
}

// Build A = elu(x*w1+b1) (MT*32 tokens x 128 k) in MFMA A-frag order:
// Apack[mt][ks][lane][j] ; m=mt*32+(lane&31), k=ks*16+(lane>>5)*8+j
template<int MT, int NTHR>
__device__ __forceinline__ void build_A(uint4* Apack, const float* __restrict__ x,
                                        const float* __restrict__ w1, const float* __restrict__ b1,
                                        int f, int tok0, int tid){
  #pragma unroll
  for (int p = 0; p < (MT*512)/NTHR; ++p){
    int slot = tid + p*NTHR;
    int l  = slot & 63;
    int ks = (slot>>6)&7;
    int mt = slot>>9;
    int m  = mt*32 + (l&31);
    int k0 = ks*16 + (l>>5)*8;
    float xv = x[(tok0+m)*NF + f];
    const float* wp = w1 + f*HH + k0;
    const float* bp = b1 + f*HH + k0;
    float4 wa = *(const float4*)wp, wb = *(const float4*)(wp+4);
    float4 ba = *(const float4*)bp, bb = *(const float4*)(bp+4);
    float h0 = eluf(fmaf(xv, wa.x, ba.x));
    float h1 = eluf(fmaf(xv, wa.y, ba.y));
    float h2 = eluf(fmaf(xv, wa.z, ba.z));
    float h3 = eluf(fmaf(xv, wa.w, ba.w));
    float h4 = eluf(fmaf(xv, wb.x, bb.x));
    float h5 = eluf(fmaf(xv, wb.y, bb.y));
    float h6 = eluf(fmaf(xv, wb.z, bb.z));
    float h7 = eluf(fmaf(xv, wb.w, bb.w));
    uint4 pk;
    pk.x = f2bf(h0) | (f2bf(h1)<<16);
    pk.y = f2bf(h2) | (f2bf(h3)<<16);
    pk.z = f2bf(h4) | (f2bf(h5)<<16);
    pk.w = f2bf(h6) | (f2bf(h7)<<16);
    Apack[slot] = pk;
  }
}

// ---------------- prep: repack w2/wg (f32) -> bf16 B-fragment layout ----------------
__global__ __launch_bounds__(256) void k_prep(const float* __restrict__ w2,
                                              const float* __restrict__ wgm,
                                              uint4* __restrict__ Wpk){
  __shared__ float ssrc[2][128][32];
  const int tid = threadIdx.x;
  const int f = blockIdx.x, c = blockIdx.y;
  #pragma unroll
  for (int it = 0; it < 32; ++it){
    int idx = tid + it*256;
    int arr = idx >> 12;
    int rem = idx & 4095;
    int k = rem >> 5, dd = rem & 31;
    const float* src = arr ? wgm : w2;
    ssrc[arr][k][dd] = src[(f*HH + k)*DM + c*32 + dd];
  }
  __syncthreads();
  #pragma unroll
  for (int p = 0; p < 4; ++p){
    int oc = tid + p*256;
    int nt = oc>>9, ks = (oc>>6)&7, l = oc&63;
    int k0 = ks*16 + (l>>5)*8, dd = l&31;
    float v[8];
    #pragma unroll
    for (int j=0;j<8;++j) v[j] = ssrc[nt][k0+j][dd];
    uint4 pk;
    pk.x = f2bf(v[0]) | (f2bf(v[1])<<16);
    pk.y = f2bf(v[2]) | (f2bf(v[3])<<16);
    pk.z = f2bf(v[4]) | (f2bf(v[5])<<16);
    pk.w = f2bf(v[6]) | (f2bf(v[7])<<16);
    Wpk[(f*8 + c)*1024 + oc] = pk;
  }
}

// ---------------- pass1: GRN + LN + store shat(fp16) + pooled sums ----------------
// 512 threads / 8 waves; 128 tokens per block. wave = (token-tile tt = wid>>1,
// d-half ch = wid&1): 32 tokens x 4 c-chunks each.
// launch_bounds (512,2): 2 blocks/CU -> 16 waves/CU, VGPR cap 128 (structure
// needs ~124 per R2 — no spill, unlike R1's (512,4) which forced 64 and spilled).
__global__ __launch_bounds__(512, 2) void k_pass1(const float* __restrict__ x,  const float* __restrict__ w1,
    const float* __restrict__ b1, const float* __restrict__ b2, const float* __restrict__ bg,
    const float* __restrict__ wsk, const float* __restrict__ bsk,
    const float* __restrict__ lng, const float* __restrict__ lnb,
    const uint4* __restrict__ Wpk,
    float* __restrict__ pooled, uint4* __restrict__ stk4){
  __shared__ uint4 smem[4096];          // 64 KB: Apack (first 2048), then fp16 stage [128 t][256 d]
  __shared__ float muL[128], rsL[128];
  __shared__ float partS[2][128], partQ[2][128];
  __shared__ float poolbuf[256];
  const int tid = threadIdx.x, lane = tid&63, wid = tid>>6;
  const int tt = wid>>1, ch = wid&1;    // token tile / d-half
  const int col = lane&31, q = lane>>5;
  const int f = blockIdx.y;
  const int tok0 = blockIdx.x*128;
  const int b = tok0 >> 9;
  if (tid < 256) poolbuf[tid] = 0.f;
  build_A<4,512>(smem, x, w1, b1, f, tok0, tid);
  __syncthreads();
  bf16x8 afr[8];
  #pragma unroll
  for (int ks=0; ks<8; ++ks) afr[ks] = __builtin_bit_cast(bf16x8, smem[(tt*8+ks)*64 + lane]);
  float xl = x[(tok0 + tt*32 + col)*NF + f];
  float xr[16];
  #pragma unroll
  for (int r=0;r<16;++r) xr[r] = qsel(xl, (r&3)+8*(r>>2), lane);
  __syncthreads();   // all Apack reads done; stage writes may begin
  __fp16* stage = (__fp16*)smem;   // [128 t][256 d]
  float sum[16], ssq[16];
  #pragma unroll
  for (int r=0;r<16;++r){ sum[r]=0.f; ssq[r]=0.f; }
  #pragma unroll
  for (int ci=0; ci<4; ++ci){
    const int c = ch*4 + ci;
    const uint4* wb = Wpk + (f*8 + c)*1024;
    bf16x8 bf0[8], bf1[8];
    #pragma unroll
    for (int ks=0;ks<8;++ks) bf0[ks] = __builtin_bit_cast(bf16x8, wb[ks*64 + lane]);
    #pragma unroll
    for (int ks=0;ks<8;++ks) bf1[ks] = __builtin_bit_cast(bf16x8, wb[512 + ks*64 + lane]);
    f32x16 acc0 = {0.f}, acc1 = {0.f};
    #pragma unroll
    for (int ks=0;ks<8;++ks){
      acc0 = __builtin_amdgcn_mfma_f32_32x32x16_bf16(afr[ks], bf0[ks], acc0, 0,0,0);
      acc1 = __builtin_amdgcn_mfma_f32_32x32x16_bf16(afr[ks], bf1[ks], acc1, 0,0,0);
    }
    const int d = c*32 + col;
    const float b2v = b2[f*DM+d], bgv = bg[f*DM+d];
    const float wsv = wsk[f*DM+d], bsv = bsk[f*DM+d];
    #pragma unroll
    for (int i=0;i<8;++i){
      const int r0 = 2*i, r1 = 2*i+1;
      const int m0 = (r0&3) + 8*(i>>1) + 4*q;
      const int t0 = tt*32 + m0;
      float sv0 = fmaf(xr[r0], wsv, bsv) + sigm(acc1[r0]+bgv)*(acc0[r0]+b2v);
      float sv1 = fmaf(xr[r1], wsv, bsv) + sigm(acc1[r1]+bgv)*(acc0[r1]+b2v);
      sum[r0] += sv0; ssq[r0] = fmaf(sv0, sv0, ssq[r0]);
      sum[r1] += sv1; ssq[r1] = fmaf(sv1, sv1, ssq[r1]);
      stage[ t0   *256 + d] = (__fp16)sv0;
      stage[(t0+1)*256 + d] = (__fp16)sv1;
    }
  }
  // LN partial stats over this wave's 128 d's: butterfly over 32 cols within q-half
  #pragma unroll
  for (int r=0;r<16;++r){
    float s1 = sum[r], s2 = ssq[r];
    s1 += __shfl_xor(s1,1);  s2 += __shfl_xor(s2,1);
    s1 += __shfl_xor(s1,2);  s2 += __shfl_xor(s2,2);
    s1 += __shfl_xor(s1,4);  s2 += __shfl_xor(s2,4);
    s1 += __shfl_xor(s1,8);  s2 += __shfl_xor(s2,8);
    s1 += __shfl_xor(s1,16); s2 += __shfl_xor(s2,16);
    sum[r] = s1;
    ssq[r] = s2;
  }
  if (col == 0){
    #pragma unroll
    for (int r=0;r<16;++r){
      int m = (r&3) + 8*(r>>2) + 4*q;
      partS[ch][tt*32 + m] = sum[r];
      partQ[ch][tt*32 + m] = ssq[r];
    }
  }
  __syncthreads();   // stage + partials complete
  if (tid < 128){
    float s1 = partS[0][tid] + partS[1][tid];
    float s2 = partQ[0][tid] + partQ[1][tid];
    float mu = s1 * (1.f/256.f);
    float var = fmaf(-mu, mu, s2*(1.f/256.f));
    muL[tid] = mu;
    rsL[tid] = rsqrtf(fmaxf(var, 0.f) + EPS);
  }
  __syncthreads();
  // dump: apply LN, write shat fp16 [f][t][d] coalesced, accumulate pooled
  const int oc = tid & 31;          // d-octet, constant per thread
  float4 ga = *(const float4*)(lng + f*DM + oc*8);
  float4 gb = *(const float4*)(lng + f*DM + oc*8 + 4);
  float4 ba = *(const float4*)(lnb + f*DM + oc*8);
  float4 bb = *(const float4*)(lnb + f*DM + oc*8 + 4);
  float gj[8] = {ga.x,ga.y,ga.z,ga.w,gb.x,gb.y,gb.z,gb.w};
  float bj[8] = {ba.x,ba.y,ba.z,ba.w,bb.x,bb.y,bb.z,bb.w};
  float ps[8];
  #pragma unroll
  for (int j=0;j<8;++j) ps[j]=0.f;
  #pragma unroll
  for (int p=0;p<8;++p){
    int slot = tid + p*512;          // [t(128)][oc(32)]
    int t = slot >> 5;
    uint4 v = smem[slot];
    f16x8 s8 = __builtin_bit_cast(f16x8, v);
    float mu = muL[t], rs = rsL[t];
    float nmr = -mu*rs;
    float sh[8];
    #pragma unroll
    for (int j=0;j<8;++j){
      sh[j] = fmaf(fmaf((float)s8[j], rs, nmr), gj[j], bj[j]);
      ps[j] += sh[j];
    }
    uint4 pk;
    pk.x = __builtin_bit_cast(unsigned, __builtin_amdgcn_cvt_pkrtz(sh[0], sh[1]));
    pk.y = __builtin_bit_cast(unsigned, __builtin_amdgcn_cvt_pkrtz(sh[2], sh[3]));
    pk.z = __builtin_bit_cast(unsigned, __builtin_amdgcn_cvt_pkrtz(sh[4], sh[5]));
    pk.w = __builtin_bit_cast(unsigned, __builtin_amdgcn_cvt_pkrtz(sh[6], sh[7]));
    stk4[(size_t)f*262144 + (size_t)(tok0 + t)*32 + oc] = pk;
  }
  #pragma unroll
  for (int j=0;j<8;++j) atomicAdd(&poolbuf[oc*8 + j], ps[j]);
  __syncthreads();
  if (tid < 256) atomicAdd(&pooled[b*8192 + f*DM + tid], poolbuf[tid]);
}

// ---------------- pass2a: flat_pooled @ W1 / @ Ws (split-K partials) ----------------
__global__ __launch_bounds__(256) void k_pass2a(const float* __restrict__ pooled,
    const float* __restrict__ W1, const float* __restrict__ Wsm,
    float* __restrict__ hw_pre, float* __restrict__ sk_pre){
  __shared__ float fl[512];
  const int tid = threadIdx.x;
  const int b = blockIdx.x;
  const int k0 = blockIdx.y * 512;
  fl[tid]       = pooled[b*8192 + k0 + tid]       * (1.f/512.f);
  fl[tid+256]   = pooled[b*8192 + k0 + tid + 256] * (1.f/512.f);
  __syncthreads();
  float acc = 0.f;
  const float* wcol = W1 + (size_t)k0*DM + tid;
  #pragma unroll 4
  for (int i=0;i<512;++i) acc = fmaf(fl[i], wcol[(size_t)i*DM], acc);
  atomicAdd(&hw_pre[b*DM + tid], acc);
  const int colj = tid & 31, sub = tid >> 5;
  float acc2 = 0.f;
  const float* wscol = Wsm + (size_t)(k0 + sub*64)*NF + colj;
  const float* fls = fl + sub*64;
  #pragma unroll 4
  for (int i=0;i<64;++i) acc2 = fmaf(fls[i], wscol[(size_t)i*NF], acc2);
  atomicAdd(&sk_pre[b*NF + colj], acc2);
}

// ---------------- pass2b: weight GRN + LN + softmax -> weights ----------------
__global__ __launch_bounds__(64) void k_pass2b(const float* __restrict__ hw_pre, const float* __restrict__ sk_pre,
    const float* __restrict__ B1, const float* __restrict__ W2, const float* __restrict__ B2,
    const float* __restrict__ Wg, const float* __restrict__ Bg, const float* __restrict__ Bs,
    const float* __restrict__ LNg, const float* __restrict__ LNb,
    float* __restrict__ out, float* __restrict__ wsel){
  __shared__ float hw[256];
  const int tid = threadIdx.x, b = blockIdx.x;
  for (int i=tid;i<256;i+=64) hw[i] = eluf(hw_pre[b*DM+i] + B1[i]);
  __syncthreads();
  if (tid < 32){
    const int j = tid;
    float ap = B2[j], ag = Bg[j];
    #pragma unroll 4
    for (int i=0;i<256;++i){ float h = hw[i]; ap = fmaf(h, W2[i*NF+j], ap); ag = fmaf(h, Wg[i*NF+j], ag); }
    float gw = sigm(ag);
    float v = sk_pre[b*NF+j] + Bs[j] + gw*ap;
    float s1 = v;
    s1 += __shfl_xor(s1,1); s1 += __shfl_xor(s1,2); s1 += __shfl_xor(s1,4); s1 += __shfl_xor(s1,8); s1 += __shfl_xor(s1,16);
    float mean = s1*(1.f/32.f);
    float dv = v - mean;
    float s2 = dv*dv;
    s2 += __shfl_xor(s2,1); s2 += __shfl_xor(s2,2); s2 += __shfl_xor(s2,4); s2 += __shfl_xor(s2,8); s2 += __shfl_xor(s2,16);
    float wn = fmaf(dv * rsqrtf(s2*(1.f/32.f) + EPS), LNg[j], LNb[j]);
    float mx = wn;
    mx = fmaxf(mx, __shfl_xor(mx,1)); mx = fmaxf(mx, __shfl_xor(mx,2)); mx = fmaxf(mx, __shfl_xor(mx,4));
    mx = fmaxf(mx, __shfl_xor(mx,8)); mx = fmaxf(mx, __shfl_xor(mx,16));
    float e = __expf(wn - mx);
    float se = e;
    se += __shfl_xor(se,1); se += __shfl_xor(se,2); se += __shfl_xor(se,4); se += __shfl_xor(se,8); se += __shfl_xor(se,16);
    float wgt = e / se;
    out[OUT_W_OFF + b*NF + j] = wgt;
    wsel[b*NF + j] = wgt;
  }
}

// ---------------- combine: out[t,d] = sum_f w[b,f] * shat[f,t,d] ----------------
// One token per wave; 16 independent uint4 loads per lane (f-half per 32-lane group).
__global__ __launch_bounds__(256) void k_comb(const uint4* __restrict__ stk4,
    const float* __restrict__ wsel, float* __restrict__ out){
  __shared__ float wloc[NF];
  const int tid = threadIdx.x, lane = tid&63;
  const int t = blockIdx.x*4 + (tid>>6);
  const int b = t >> 9;
  if (tid < NF) wloc[tid] = wsel[b*NF + tid];
  __syncthreads();
  const int oc = lane&31, fh = lane>>5;
  float acc[8];
  #pragma unroll
  for (int j=0;j<8;++j) acc[j]=0.f;
  #pragma unroll
  for (int j=0;j<16;++j){
    int f = fh*16 + j;
    uint4 v = stk4[(size_t)f*262144 + (size_t)t*32 + oc];
    f16x8 hv = __builtin_bit_cast(f16x8, v);
    float wf = wloc[f];
    #pragma unroll
    for (int jj=0;jj<8;++jj) acc[jj] = fmaf(wf, (float)hv[jj], acc[jj]);
  }
  #pragma unroll
  for (int jj=0;jj<8;++jj) acc[jj] += __shfl_xor(acc[jj], 32);
  if (fh == 0){
    float4* o = (float4*)(out + (size_t)t*DM + oc*8);
    o[0] = make_float4(acc[0],acc[1],acc[2],acc[3]);
    o[1] = make_float4(acc[4],acc[5],acc[6],acc[7]);
  }
}

extern "C" void kernel_launch(void* const* d_in, const int* in_sizes, int n_in,
                              void* d_out, int out_size, void* d_ws, size_t ws_size,
                              hipStream_t stream) {
  const float* x   = (const float*)d_in[0];
  const float* w1  = (const float*)d_in[1];
  const float* b1  = (const float*)d_in[2];
  const float* w2  = (const float*)d_in[3];
  const float* b2  = (const float*)d_in[4];
  const float* wgm = (const float*)d_in[5];
  const float* bg  = (const float*)d_in[6];
  const float* wsk = (const float*)d_in[7];
  const float* bsk = (const float*)d_in[8];
  const float* lng = (const float*)d_in[9];
  const float* lnb = (const float*)d_in[10];
  const float* W1  = (const float*)d_in[11];
  const float* B1  = (const float*)d_in[12];
  const float* W2  = (const float*)d_in[13];
  const float* B2  = (const float*)d_in[14];
  const float* Wg  = (const float*)d_in[15];
  const float* Bg  = (const float*)d_in[16];
  const float* Wsm = (const float*)d_in[17];
  const float* Bs  = (const float*)d_in[18];
  const float* LNg = (const float*)d_in[19];
  const float* LNb = (const float*)d_in[20];
  float* out = (float*)d_out;

  char* ws = (char*)d_ws;
  uint4* Wpk    = (uint4*)ws;                     // 4 MB bf16-packed weights
  uint4* stk4   = (uint4*)(ws + 4194304);         // 128 MiB fp16 shat [f][t][d]
  float* pooled = (float*)(ws + 138412032);       // 512 KB
  float* hw_pre = (float*)(ws + 138936320);       // 16 KB
  float* sk_pre = (float*)(ws + 138952704);       // 2 KB
  float* wsel   = (float*)(ws + 138954752);       // 2 KB

  (void)hipMemsetAsync(pooled, 0, 524288, stream);
  (void)hipMemsetAsync(hw_pre, 0, 16384 + 2048, stream);

  k_prep<<<dim3(32,8), 256, 0, stream>>>(w2, wgm, Wpk);
  k_pass1<<<dim3(64,32), 512, 0, stream>>>(x, w1, b1, b2, bg, wsk, bsk, lng, lnb,
                                           Wpk, pooled, stk4);
  k_pass2a<<<dim3(16,16), 256, 0, stream>>>(pooled, W1, Wsm, hw_pre, sk_pre);
  k_pass2b<<<16, 64, 0, stream>>>(hw_pre, sk_pre, B1, W2, B2, Wg, Bg, Bs, LNg, LNb, out, wsel);
  k_comb<<<2048, 256, 0, stream>>>(stk4, wsel, out);
}

// Round 4
// 325.511 us; speedup vs baseline: 1.2307x; 1.2307x over previous
//
#include <hip/hip_runtime.h>
#include <hip/hip_fp16.h>

// Problem constants
#define NF 32
#define DM 256
#define HH 128
#define BB 16
#define TT 512
#define BT 8192            // B*T tokens
#define OUT_W_OFF 2097152  // B*T*D
#define EPS 1e-5f

typedef __bf16 bf16x8 __attribute__((ext_vector_type(8)));
typedef float  f32x16 __attribute__((ext_vector_type(16)));
typedef __fp16 f16x2 __attribute__((ext_vector_type(2)));
typedef __fp16 f16x8 __attribute__((ext_vector_type(8)));

__device__ __forceinline__ float eluf(float z){ return z > 0.f ? z : __expf(z) - 1.f; }
__device__ __forceinline__ float sigm(float z){ return 1.f/(1.f + __expf(-z)); }
__device__ __forceinline__ unsigned f2bf(float x){
  unsigned u = __float_as_uint(x);
  u += 0x7fffu + ((u>>16)&1u);   // RNE
  return u>>16;
}

// ---------------- prep: repack w2/wg (f32) -> bf16 B-fragment layout ----------------
__global__ __launch_bounds__(256) void k_prep(const float* __restrict__ w2,
                                              const float* __restrict__ wgm,
                                              uint4* __restrict__ Wpk){
  __shared__ float ssrc[2][128][32];
  const int tid = threadIdx.x;
  const int f = blockIdx.x, c = blockIdx.y;
  #pragma unroll
  for (int it = 0; it < 32; ++it){
    int idx = tid + it*256;
    int arr = idx >> 12;
    int rem = idx & 4095;
    int k = rem >> 5, dd = rem & 31;
    const float* src = arr ? wgm : w2;
    ssrc[arr][k][dd] = src[(f*HH + k)*DM + c*32 + dd];
  }
  __syncthreads();
  #pragma unroll
  for (int p = 0; p < 4; ++p){
    int oc = tid + p*256;
    int nt = oc>>9, ks = (oc>>6)&7, l = oc&63;
    int k0 = ks*16 + (l>>5)*8, dd = l&31;
    float v[8];
    #pragma unroll
    for (int j=0;j<8;++j) v[j] = ssrc[nt][k0+j][dd];
    uint4 pk;
    pk.x = f2bf(v[0]) | (f2bf(v[1])<<16);
    pk.y = f2bf(v[2]) | (f2bf(v[3])<<16);
    pk.z = f2bf(v[4]) | (f2bf(v[5])<<16);
    pk.w = f2bf(v[6]) | (f2bf(v[7])<<16);
    Wpk[(f*8 + c)*1024 + oc] = pk;
  }
}

// ---------------- pass1: GRN + LN + store shat(fp16) + pooled sums ----------------
// 512 threads / 8 waves; 128 tokens. wave = (tt = wid>>1, ch = wid&1):
// 32 tokens x 4 c-chunks. Register diet (target arch VGPR <= 96 so that
// VGPR+32 AGPR rounds to 128 -> 4 waves/SIMD, 2 blocks/CU = 16 waves/CU):
//  - A-fragments built directly in registers from global w1/b1 (L1-hot)
//  - no sum/ssq accumulators: LN stats computed in the dump phase via
//    32-lane shfl tree (each 32-lane group owns a full token row)
//  - no xr[] / qsel: skip term x*ws+bs applied in dump (x via 512B LDS)
//  - sequential acc0/acc1 MFMA batches + sched_barrier fences pin the
//    B-fragment live set to 32 regs
__global__ __launch_bounds__(512, 2) void k_pass1(const float* __restrict__ x,  const float* __restrict__ w1,
    const float* __restrict__ b1, const float* __restrict__ b2, const float* __restrict__ bg,
    const float* __restrict__ wsk, const float* __restrict__ bsk,
    const float* __restrict__ lng, const float* __restrict__ lnb,
    const uint4* __restrict__ Wpk,
    float* __restrict__ pooled, uint4* __restrict__ stk4){
  __shared__ uint4 smem[4096];          // 64 KB fp16 stage [128 t][256 d]
  __shared__ float xs[128];
  __shared__ float poolbuf[256];
  const int tid = threadIdx.x, lane = tid&63, wid = tid>>6;
  const int tt = wid>>1, ch = wid&1;    // token tile / d-half
  const int col = lane&31, q = lane>>5;
  const int f = blockIdx.y;
  const int tok0 = blockIdx.x*128;
  const int b = tok0 >> 9;
  if (tid < 256) poolbuf[tid] = 0.f;

  // --- build A-fragments in registers: token m = tt*32+col, k0 = ks*16+q*8 ---
  const float xv = x[(tok0 + tt*32 + col)*NF + f];
  if (ch == 0 && q == 0) xs[tt*32 + col] = xv;
  bf16x8 afr[8];
  {
    const float* wp0 = w1 + f*HH + q*8;
    const float* bp0 = b1 + f*HH + q*8;
    #pragma unroll
    for (int ks=0; ks<8; ++ks){
      float4 wa = *(const float4*)(wp0 + ks*16);
      float4 wbv = *(const float4*)(wp0 + ks*16 + 4);
      float4 ba = *(const float4*)(bp0 + ks*16);
      float4 bbv = *(const float4*)(bp0 + ks*16 + 4);
      uint4 pk;
      pk.x = f2bf(eluf(fmaf(xv, wa.x,  ba.x ))) | (f2bf(eluf(fmaf(xv, wa.y,  ba.y )))<<16);
      pk.y = f2bf(eluf(fmaf(xv, wa.z,  ba.z ))) | (f2bf(eluf(fmaf(xv, wa.w,  ba.w )))<<16);
      pk.z = f2bf(eluf(fmaf(xv, wbv.x, bbv.x))) | (f2bf(eluf(fmaf(xv, wbv.y, bbv.y)))<<16);
      pk.w = f2bf(eluf(fmaf(xv, wbv.z, bbv.z))) | (f2bf(eluf(fmaf(xv, wbv.w, bbv.w)))<<16);
      afr[ks] = __builtin_bit_cast(bf16x8, pk);
    }
  }

  __fp16* stage = (__fp16*)smem;        // [128 t][256 d]
  #pragma unroll 1
  for (int ci=0; ci<4; ++ci){
    const int c = ch*4 + ci;
    const uint4* wb = Wpk + (f*8 + c)*1024;
    bf16x8 bfr[8];
    #pragma unroll
    for (int ks=0;ks<8;++ks) bfr[ks] = __builtin_bit_cast(bf16x8, wb[ks*64 + lane]);
    f32x16 acc0 = {0.f};
    #pragma unroll
    for (int ks=0;ks<8;++ks) acc0 = __builtin_amdgcn_mfma_f32_32x32x16_bf16(afr[ks], bfr[ks], acc0, 0,0,0);
    __builtin_amdgcn_sched_barrier(0);  // keep second B-batch from hoisting (reg pressure)
    #pragma unroll
    for (int ks=0;ks<8;++ks) bfr[ks] = __builtin_bit_cast(bf16x8, wb[512 + ks*64 + lane]);
    f32x16 acc1 = {0.f};
    #pragma unroll
    for (int ks=0;ks<8;++ks) acc1 = __builtin_amdgcn_mfma_f32_32x32x16_bf16(afr[ks], bfr[ks], acc1, 0,0,0);
    __builtin_amdgcn_sched_barrier(0);
    const int d = c*32 + col;
    const float b2v = b2[f*DM+d], bgv = bg[f*DM+d];
    #pragma unroll
    for (int i=0;i<8;++i){
      const int r0 = 2*i, r1 = r0+1;
      const int t0 = tt*32 + (r0&3) + 8*(i>>1) + 4*q;
      stage[ t0   *256 + d] = (__fp16)(sigm(acc1[r0]+bgv)*(acc0[r0]+b2v));
      stage[(t0+1)*256 + d] = (__fp16)(sigm(acc1[r1]+bgv)*(acc0[r1]+b2v));
    }
  }
  __syncthreads();   // stage + xs complete

  // --- dump: add skip, LN stats via 32-lane tree, apply LN, write + pool ---
  const int oc = tid & 31;          // d-octet, constant per thread
  float4 ga = *(const float4*)(lng + f*DM + oc*8);
  float4 gb = *(const float4*)(lng + f*DM + oc*8 + 4);
  float4 la = *(const float4*)(lnb + f*DM + oc*8);
  float4 lb = *(const float4*)(lnb + f*DM + oc*8 + 4);
  float4 wa = *(const float4*)(wsk + f*DM + oc*8);
  float4 wbv = *(const float4*)(wsk + f*DM + oc*8 + 4);
  float4 sa = *(const float4*)(bsk + f*DM + oc*8);
  float4 sb = *(const float4*)(bsk + f*DM + oc*8 + 4);
  float gj[8] = {ga.x,ga.y,ga.z,ga.w,gb.x,gb.y,gb.z,gb.w};
  float bj[8] = {la.x,la.y,la.z,la.w,lb.x,lb.y,lb.z,lb.w};
  float wj[8] = {wa.x,wa.y,wa.z,wa.w,wbv.x,wbv.y,wbv.z,wbv.w};
  float cj[8] = {sa.x,sa.y,sa.z,sa.w,sb.x,sb.y,sb.z,sb.w};
  float ps[8];
  #pragma unroll
  for (int j=0;j<8;++j) ps[j]=0.f;
  #pragma unroll
  for (int p=0;p<8;++p){
    int slot = tid + p*512;          // [t(128)][oc(32)]
    int t = slot >> 5;
    uint4 v = smem[slot];
    f16x8 s8 = __builtin_bit_cast(f16x8, v);
    float xt = xs[t];
    float s[8];
    float ssum = 0.f, ssq = 0.f;
    #pragma unroll
    for (int j=0;j<8;++j){
      s[j] = fmaf(xt, wj[j], cj[j]) + (float)s8[j];
      ssum += s[j];
      ssq = fmaf(s[j], s[j], ssq);
    }
    // token row t is fully owned by this 32-lane group
    ssum += __shfl_xor(ssum,1);  ssq += __shfl_xor(ssq,1);
    ssum += __shfl_xor(ssum,2);  ssq += __shfl_xor(ssq,2);
    ssum += __shfl_xor(ssum,4);  ssq += __shfl_xor(ssq,4);
    ssum += __shfl_xor(ssum,8);  ssq += __shfl_xor(ssq,8);
    ssum += __shfl_xor(ssum,16); ssq += __shfl_xor(ssq,16);
    float mu = ssum * (1.f/256.f);
    float var = fmaf(-mu, mu, ssq*(1.f/256.f));
    float rs = rsqrtf(fmaxf(var, 0.f) + EPS);
    float nmr = -mu*rs;
    float sh[8];
    #pragma unroll
    for (int j=0;j<8;++j){
      sh[j] = fmaf(fmaf(s[j], rs, nmr), gj[j], bj[j]);
      ps[j] += sh[j];
    }
    uint4 pk;
    pk.x = __builtin_bit_cast(unsigned, __builtin_amdgcn_cvt_pkrtz(sh[0], sh[1]));
    pk.y = __builtin_bit_cast(unsigned, __builtin_amdgcn_cvt_pkrtz(sh[2], sh[3]));
    pk.z = __builtin_bit_cast(unsigned, __builtin_amdgcn_cvt_pkrtz(sh[4], sh[5]));
    pk.w = __builtin_bit_cast(unsigned, __builtin_amdgcn_cvt_pkrtz(sh[6], sh[7]));
    stk4[(size_t)f*262144 + (size_t)(tok0 + t)*32 + oc] = pk;
  }
  // fold lane pairs (l, l+32) sharing oc, then one LDS atomic per cell
  #pragma unroll
  for (int j=0;j<8;++j) ps[j] += __shfl_xor(ps[j], 32);
  if (q == 0){
    #pragma unroll
    for (int j=0;j<8;++j) atomicAdd(&poolbuf[oc*8 + j], ps[j]);
  }
  __syncthreads();
  if (tid < 256) atomicAdd(&pooled[b*8192 + f*DM + tid], poolbuf[tid]);
}

// ---------------- pass2a: flat_pooled @ W1 / @ Ws (split-K partials) ----------------
__global__ __launch_bounds__(256) void k_pass2a(const float* __restrict__ pooled,
    const float* __restrict__ W1, const float* __restrict__ Wsm,
    float* __restrict__ hw_pre, float* __restrict__ sk_pre){
  __shared__ float fl[512];
  const int tid = threadIdx.x;
  const int b = blockIdx.x;
  const int k0 = blockIdx.y * 512;
  fl[tid]       = pooled[b*8192 + k0 + tid]       * (1.f/512.f);
  fl[tid+256]   = pooled[b*8192 + k0 + tid + 256] * (1.f/512.f);
  __syncthreads();
  float acc = 0.f;
  const float* wcol = W1 + (size_t)k0*DM + tid;
  #pragma unroll 4
  for (int i=0;i<512;++i) acc = fmaf(fl[i], wcol[(size_t)i*DM], acc);
  atomicAdd(&hw_pre[b*DM + tid], acc);
  const int colj = tid & 31, sub = tid >> 5;
  float acc2 = 0.f;
  const float* wscol = Wsm + (size_t)(k0 + sub*64)*NF + colj;
  const float* fls = fl + sub*64;
  #pragma unroll 4
  for (int i=0;i<64;++i) acc2 = fmaf(fls[i], wscol[(size_t)i*NF], acc2);
  atomicAdd(&sk_pre[b*NF + colj], acc2);
}

// ---------------- pass2b: weight GRN + LN + softmax -> weights ----------------
__global__ __launch_bounds__(64) void k_pass2b(const float* __restrict__ hw_pre, const float* __restrict__ sk_pre,
    const float* __restrict__ B1, const float* __restrict__ W2, const float* __restrict__ B2,
    const float* __restrict__ Wg, const float* __restrict__ Bg, const float* __restrict__ Bs,
    const float* __restrict__ LNg, const float* __restrict__ LNb,
    float* __restrict__ out, float* __restrict__ wsel){
  __shared__ float hw[256];
  const int tid = threadIdx.x, b = blockIdx.x;
  for (int i=tid;i<256;i+=64) hw[i] = eluf(hw_pre[b*DM+i] + B1[i]);
  __syncthreads();
  if (tid < 32){
    const int j = tid;
    float ap = B2[j], ag = Bg[j];
    #pragma unroll 4
    for (int i=0;i<256;++i){ float h = hw[i]; ap = fmaf(h, W2[i*NF+j], ap); ag = fmaf(h, Wg[i*NF+j], ag); }
    float gw = sigm(ag);
    float v = sk_pre[b*NF+j] + Bs[j] + gw*ap;
    float s1 = v;
    s1 += __shfl_xor(s1,1); s1 += __shfl_xor(s1,2); s1 += __shfl_xor(s1,4); s1 += __shfl_xor(s1,8); s1 += __shfl_xor(s1,16);
    float mean = s1*(1.f/32.f);
    float dv = v - mean;
    float s2 = dv*dv;
    s2 += __shfl_xor(s2,1); s2 += __shfl_xor(s2,2); s2 += __shfl_xor(s2,4); s2 += __shfl_xor(s2,8); s2 += __shfl_xor(s2,16);
    float wn = fmaf(dv * rsqrtf(s2*(1.f/32.f) + EPS), LNg[j], LNb[j]);
    float mx = wn;
    mx = fmaxf(mx, __shfl_xor(mx,1)); mx = fmaxf(mx, __shfl_xor(mx,2)); mx = fmaxf(mx, __shfl_xor(mx,4));
    mx = fmaxf(mx, __shfl_xor(mx,8)); mx = fmaxf(mx, __shfl_xor(mx,16));
    float e = __expf(wn - mx);
    float se = e;
    se += __shfl_xor(se,1); se += __shfl_xor(se,2); se += __shfl_xor(se,4); se += __shfl_xor(se,8); se += __shfl_xor(se,16);
    float wgt = e / se;
    out[OUT_W_OFF + b*NF + j] = wgt;
    wsel[b*NF + j] = wgt;
  }
}

// ---------------- combine: out[t,d] = sum_f w[b,f] * shat[f,t,d] ----------------
// One token per wave; 16 independent uint4 loads per lane (f-half per 32-lane group).
__global__ __launch_bounds__(256) void k_comb(const uint4* __restrict__ stk4,
    const float* __restrict__ wsel, float* __restrict__ out){
  __shared__ float wloc[NF];
  const int tid = threadIdx.x, lane = tid&63;
  const int t = blockIdx.x*4 + (tid>>6);
  const int b = t >> 9;
  if (tid < NF) wloc[tid] = wsel[b*NF + tid];
  __syncthreads();
  const int oc = lane&31, fh = lane>>5;
  float acc[8];
  #pragma unroll
  for (int j=0;j<8;++j) acc[j]=0.f;
  #pragma unroll
  for (int j=0;j<16;++j){
    int f = fh*16 + j;
    uint4 v = stk4[(size_t)f*262144 + (size_t)t*32 + oc];
    f16x8 hv = __builtin_bit_cast(f16x8, v);
    float wf = wloc[f];
    #pragma unroll
    for (int jj=0;jj<8;++jj) acc[jj] = fmaf(wf, (float)hv[jj], acc[jj]);
  }
  #pragma unroll
  for (int jj=0;jj<8;++jj) acc[jj] += __shfl_xor(acc[jj], 32);
  if (fh == 0){
    float4* o = (float4*)(out + (size_t)t*DM + oc*8);
    o[0] = make_float4(acc[0],acc[1],acc[2],acc[3]);
    o[1] = make_float4(acc[4],acc[5],acc[6],acc[7]);
  }
}

extern "C" void kernel_launch(void* const* d_in, const int* in_sizes, int n_in,
                              void* d_out, int out_size, void* d_ws, size_t ws_size,
                              hipStream_t stream) {
  const float* x   = (const float*)d_in[0];
  const float* w1  = (const float*)d_in[1];
  const float* b1  = (const float*)d_in[2];
  const float* w2  = (const float*)d_in[3];
  const float* b2  = (const float*)d_in[4];
  const float* wgm = (const float*)d_in[5];
  const float* bg  = (const float*)d_in[6];
  const float* wsk = (const float*)d_in[7];
  const float* bsk = (const float*)d_in[8];
  const float* lng = (const float*)d_in[9];
  const float* lnb = (const float*)d_in[10];
  const float* W1  = (const float*)d_in[11];
  const float* B1  = (const float*)d_in[12];
  const float* W2  = (const float*)d_in[13];
  const float* B2  = (const float*)d_in[14];
  const float* Wg  = (const float*)d_in[15];
  const float* Bg  = (const float*)d_in[16];
  const float* Wsm = (const float*)d_in[17];
  const float* Bs  = (const float*)d_in[18];
  const float* LNg = (const float*)d_in[19];
  const float* LNb = (const float*)d_in[20];
  float* out = (float*)d_out;

  char* ws = (char*)d_ws;
  uint4* Wpk    = (uint4*)ws;                     // 4 MB bf16-packed weights
  uint4* stk4   = (uint4*)(ws + 4194304);         // 128 MiB fp16 shat [f][t][d]
  float* pooled = (float*)(ws + 138412032);       // 512 KB
  float* hw_pre = (float*)(ws + 138936320);       // 16 KB
  float* sk_pre = (float*)(ws + 138952704);       // 2 KB
  float* wsel   = (float*)(ws + 138954752);       // 2 KB

  (void)hipMemsetAsync(pooled, 0, 524288, stream);
  (void)hipMemsetAsync(hw_pre, 0, 16384 + 2048, stream);

  k_prep<<<dim3(32,8), 256, 0, stream>>>(w2, wgm, Wpk);
  k_pass1<<<dim3(64,32), 512, 0, stream>>>(x, w1, b1, b2, bg, wsk, bsk, lng, lnb,
                                           Wpk, pooled, stk4);
  k_pass2a<<<dim3(16,16), 256, 0, stream>>>(pooled, W1, Wsm, hw_pre, sk_pre);
  k_pass2b<<<16, 64, 0, stream>>>(hw_pre, sk_pre, B1, W2, B2, Wg, Bg, Bs, LNg, LNb, out, wsel);
  k_comb<<<2048, 256, 0, stream>>>(stk4, wsel, out);
}

// Round 5
// 302.626 us; speedup vs baseline: 1.3238x; 1.0756x over previous
//
#include <hip/hip_runtime.h>
#include <hip/hip_fp16.h>

// Problem constants
#define NF 32
#define DM 256
#define HH 128
#define BB 16
#define TT 512
#define BT 8192            // B*T tokens
#define OUT_W_OFF 2097152  // B*T*D
#define EPS 1e-5f

typedef __bf16 bf16x8 __attribute__((ext_vector_type(8)));
typedef float  f32x16 __attribute__((ext_vector_type(16)));
typedef __fp16 f16x2 __attribute__((ext_vector_type(2)));
typedef __fp16 f16x8 __attribute__((ext_vector_type(8)));

__device__ __forceinline__ float eluf(float z){ return z > 0.f ? z : __expf(z) - 1.f; }
__device__ __forceinline__ float sigm(float z){ return 1.f/(1.f + __expf(-z)); }
__device__ __forceinline__ unsigned f2bf(float x){
  unsigned u = __float_as_uint(x);
  u += 0x7fffu + ((u>>16)&1u);   // RNE
  return u>>16;
}

// Build A = elu(x*w1+b1) (MT*32 tokens x 128 k) in MFMA A-frag order, shared via LDS:
// Apack[mt][ks][lane][j] ; m=mt*32+(lane&31), k=ks*16+(lane>>5)*8+j
// Native (__bf16) casts -> hardware cvt (1-2 ops/elem vs ~4 for manual RNE).
template<int MT, int NTHR>
__device__ __forceinline__ void build_A(uint4* Apack, const float* __restrict__ x,
                                        const float* __restrict__ w1, const float* __restrict__ b1,
                                        int f, int tok0, int tid){
  #pragma unroll
  for (int p = 0; p < (MT*512)/NTHR; ++p){
    int slot = tid + p*NTHR;
    int l  = slot & 63;
    int ks = (slot>>6)&7;
    int mt = slot>>9;
    int m  = mt*32 + (l&31);
    int k0 = ks*16 + (l>>5)*8;
    float xv = x[(tok0+m)*NF + f];
    const float* wp = w1 + f*HH + k0;
    const float* bp = b1 + f*HH + k0;
    float4 wa = *(const float4*)wp, wb = *(const float4*)(wp+4);
    float4 ba = *(const float4*)bp, bb = *(const float4*)(bp+4);
    bf16x8 v;
    v[0] = (__bf16)eluf(fmaf(xv, wa.x, ba.x));
    v[1] = (__bf16)eluf(fmaf(xv, wa.y, ba.y));
    v[2] = (__bf16)eluf(fmaf(xv, wa.z, ba.z));
    v[3] = (__bf16)eluf(fmaf(xv, wa.w, ba.w));
    v[4] = (__bf16)eluf(fmaf(xv, wb.x, bb.x));
    v[5] = (__bf16)eluf(fmaf(xv, wb.y, bb.y));
    v[6] = (__bf16)eluf(fmaf(xv, wb.z, bb.z));
    v[7] = (__bf16)eluf(fmaf(xv, wb.w, bb.w));
    Apack[slot] = __builtin_bit_cast(uint4, v);
  }
}

// ---------------- prep: repack w2/wg (f32) -> bf16 B-fragment layout ----------------
__global__ __launch_bounds__(256) void k_prep(const float* __restrict__ w2,
                                              const float* __restrict__ wgm,
                                              uint4* __restrict__ Wpk){
  __shared__ float ssrc[2][128][32];
  const int tid = threadIdx.x;
  const int f = blockIdx.x, c = blockIdx.y;
  #pragma unroll
  for (int it = 0; it < 32; ++it){
    int idx = tid + it*256;
    int arr = idx >> 12;
    int rem = idx & 4095;
    int k = rem >> 5, dd = rem & 31;
    const float* src = arr ? wgm : w2;
    ssrc[arr][k][dd] = src[(f*HH + k)*DM + c*32 + dd];
  }
  __syncthreads();
  #pragma unroll
  for (int p = 0; p < 4; ++p){
    int oc = tid + p*256;
    int nt = oc>>9, ks = (oc>>6)&7, l = oc&63;
    int k0 = ks*16 + (l>>5)*8, dd = l&31;
    float v[8];
    #pragma unroll
    for (int j=0;j<8;++j) v[j] = ssrc[nt][k0+j][dd];
    uint4 pk;
    pk.x = f2bf(v[0]) | (f2bf(v[1])<<16);
    pk.y = f2bf(v[2]) | (f2bf(v[3])<<16);
    pk.z = f2bf(v[4]) | (f2bf(v[5])<<16);
    pk.w = f2bf(v[6]) | (f2bf(v[7])<<16);
    Wpk[(f*8 + c)*1024 + oc] = pk;
  }
}

// ---------------- pass1: GRN + LN + store shat(fp16) + pooled sums ----------------
// 512 threads / 8 waves; 128 tokens. wave = (tt = wid>>1, ch = wid&1):
// 32 tokens x 4 c-chunks. VGPR 60 + 32 AGPR -> 128-class -> 4 waves/SIMD,
// 2 blocks/CU (LDS-bound) = 16 waves/CU (R4-verified: occ 40.7%).
// R5: build_A shared via LDS (was duplicated per d-half wave: halves elu/trans
// and VMEM in the build phase) + native bf16 casts (was manual RNE bit math).
__global__ __launch_bounds__(512, 2) void k_pass1(const float* __restrict__ x,  const float* __restrict__ w1,
    const float* __restrict__ b1, const float* __restrict__ b2, const float* __restrict__ bg,
    const float* __restrict__ wsk, const float* __restrict__ bsk,
    const float* __restrict__ lng, const float* __restrict__ lnb,
    const uint4* __restrict__ Wpk,
    float* __restrict__ pooled, uint4* __restrict__ stk4){
  __shared__ uint4 smem[4096];          // 64 KB: Apack (first 2048 = 32 KB), then fp16 stage [128 t][256 d]
  __shared__ float xs[128];
  __shared__ float poolbuf[256];
  const int tid = threadIdx.x, lane = tid&63, wid = tid>>6;
  const int tt = wid>>1, ch = wid&1;    // token tile / d-half
  const int col = lane&31, q = lane>>5;
  const int f = blockIdx.y;
  const int tok0 = blockIdx.x*128;
  const int b = tok0 >> 9;
  if (tid < 256) poolbuf[tid] = 0.f;
  if (tid < 128) xs[tid] = x[(tok0 + tid)*NF + f];

  build_A<4,512>(smem, x, w1, b1, f, tok0, tid);
  __syncthreads();
  bf16x8 afr[8];
  #pragma unroll
  for (int ks=0; ks<8; ++ks) afr[ks] = __builtin_bit_cast(bf16x8, smem[(tt*8+ks)*64 + lane]);
  __syncthreads();   // all Apack reads done; stage writes may begin

  __fp16* stage = (__fp16*)smem;        // [128 t][256 d]
  #pragma unroll 1
  for (int ci=0; ci<4; ++ci){
    const int c = ch*4 + ci;
    const uint4* wb = Wpk + (f*8 + c)*1024;
    bf16x8 bfr[8];
    #pragma unroll
    for (int ks=0;ks<8;++ks) bfr[ks] = __builtin_bit_cast(bf16x8, wb[ks*64 + lane]);
    f32x16 acc0 = {0.f};
    #pragma unroll
    for (int ks=0;ks<8;++ks) acc0 = __builtin_amdgcn_mfma_f32_32x32x16_bf16(afr[ks], bfr[ks], acc0, 0,0,0);
    __builtin_amdgcn_sched_barrier(0);  // keep second B-batch from hoisting (reg pressure)
    #pragma unroll
    for (int ks=0;ks<8;++ks) bfr[ks] = __builtin_bit_cast(bf16x8, wb[512 + ks*64 + lane]);
    f32x16 acc1 = {0.f};
    #pragma unroll
    for (int ks=0;ks<8;++ks) acc1 = __builtin_amdgcn_mfma_f32_32x32x16_bf16(afr[ks], bfr[ks], acc1, 0,0,0);
    __builtin_amdgcn_sched_barrier(0);
    const int d = c*32 + col;
    const float b2v = b2[f*DM+d], bgv = bg[f*DM+d];
    #pragma unroll
    for (int i=0;i<8;++i){
      const int r0 = 2*i, r1 = r0+1;
      const int t0 = tt*32 + (r0&3) + 8*(i>>1) + 4*q;
      stage[ t0   *256 + d] = (__fp16)(sigm(acc1[r0]+bgv)*(acc0[r0]+b2v));
      stage[(t0+1)*256 + d] = (__fp16)(sigm(acc1[r1]+bgv)*(acc0[r1]+b2v));
    }
  }
  __syncthreads();   // stage + xs complete

  // --- dump: add skip, LN stats via 32-lane tree, apply LN, write + pool ---
  const int oc = tid & 31;          // d-octet, constant per thread
  float4 ga = *(const float4*)(lng + f*DM + oc*8);
  float4 gb = *(const float4*)(lng + f*DM + oc*8 + 4);
  float4 la = *(const float4*)(lnb + f*DM + oc*8);
  float4 lb = *(const float4*)(lnb + f*DM + oc*8 + 4);
  float4 wa = *(const float4*)(wsk + f*DM + oc*8);
  float4 wbv = *(const float4*)(wsk + f*DM + oc*8 + 4);
  float4 sa = *(const float4*)(bsk + f*DM + oc*8);
  float4 sb = *(const float4*)(bsk + f*DM + oc*8 + 4);
  float gj[8] = {ga.x,ga.y,ga.z,ga.w,gb.x,gb.y,gb.z,gb.w};
  float bj[8] = {la.x,la.y,la.z,la.w,lb.x,lb.y,lb.z,lb.w};
  float wj[8] = {wa.x,wa.y,wa.z,wa.w,wbv.x,wbv.y,wbv.z,wbv.w};
  float cj[8] = {sa.x,sa.y,sa.z,sa.w,sb.x,sb.y,sb.z,sb.w};
  float ps[8];
  #pragma unroll
  for (int j=0;j<8;++j) ps[j]=0.f;
  #pragma unroll
  for (int p=0;p<8;++p){
    int slot = tid + p*512;          // [t(128)][oc(32)]
    int t = slot >> 5;
    uint4 v = smem[slot];
    f16x8 s8 = __builtin_bit_cast(f16x8, v);
    float xt = xs[t];
    float s[8];
    float ssum = 0.f, ssq = 0.f;
    #pragma unroll
    for (int j=0;j<8;++j){
      s[j] = fmaf(xt, wj[j], cj[j]) + (float)s8[j];
      ssum += s[j];
      ssq = fmaf(s[j], s[j], ssq);
    }
    // token row t is fully owned by this 32-lane group
    ssum += __shfl_xor(ssum,1);  ssq += __shfl_xor(ssq,1);
    ssum += __shfl_xor(ssum,2);  ssq += __shfl_xor(ssq,2);
    ssum += __shfl_xor(ssum,4);  ssq += __shfl_xor(ssq,4);
    ssum += __shfl_xor(ssum,8);  ssq += __shfl_xor(ssq,8);
    ssum += __shfl_xor(ssum,16); ssq += __shfl_xor(ssq,16);
    float mu = ssum * (1.f/256.f);
    float var = fmaf(-mu, mu, ssq*(1.f/256.f));
    float rs = rsqrtf(fmaxf(var, 0.f) + EPS);
    float nmr = -mu*rs;
    float sh[8];
    #pragma unroll
    for (int j=0;j<8;++j){
      sh[j] = fmaf(fmaf(s[j], rs, nmr), gj[j], bj[j]);
      ps[j] += sh[j];
    }
    uint4 pk;
    pk.x = __builtin_bit_cast(unsigned, __builtin_amdgcn_cvt_pkrtz(sh[0], sh[1]));
    pk.y = __builtin_bit_cast(unsigned, __builtin_amdgcn_cvt_pkrtz(sh[2], sh[3]));
    pk.z = __builtin_bit_cast(unsigned, __builtin_amdgcn_cvt_pkrtz(sh[4], sh[5]));
    pk.w = __builtin_bit_cast(unsigned, __builtin_amdgcn_cvt_pkrtz(sh[6], sh[7]));
    stk4[(size_t)f*262144 + (size_t)(tok0 + t)*32 + oc] = pk;
  }
  // fold lane pairs (l, l+32) sharing oc, then one LDS atomic per cell
  #pragma unroll
  for (int j=0;j<8;++j) ps[j] += __shfl_xor(ps[j], 32);
  if (q == 0){
    #pragma unroll
    for (int j=0;j<8;++j) atomicAdd(&poolbuf[oc*8 + j], ps[j]);
  }
  __syncthreads();
  if (tid < 256) atomicAdd(&pooled[b*8192 + f*DM + tid], poolbuf[tid]);
}

// ---------------- pass2a: flat_pooled @ W1 / @ Ws (split-K partials) ----------------
__global__ __launch_bounds__(256) void k_pass2a(const float* __restrict__ pooled,
    const float* __restrict__ W1, const float* __restrict__ Wsm,
    float* __restrict__ hw_pre, float* __restrict__ sk_pre){
  __shared__ float fl[512];
  const int tid = threadIdx.x;
  const int b = blockIdx.x;
  const int k0 = blockIdx.y * 512;
  fl[tid]       = pooled[b*8192 + k0 + tid]       * (1.f/512.f);
  fl[tid+256]   = pooled[b*8192 + k0 + tid + 256] * (1.f/512.f);
  __syncthreads();
  float acc = 0.f;
  const float* wcol = W1 + (size_t)k0*DM + tid;
  #pragma unroll 4
  for (int i=0;i<512;++i) acc = fmaf(fl[i], wcol[(size_t)i*DM], acc);
  atomicAdd(&hw_pre[b*DM + tid], acc);
  const int colj = tid & 31, sub = tid >> 5;
  float acc2 = 0.f;
  const float* wscol = Wsm + (size_t)(k0 + sub*64)*NF + colj;
  const float* fls = fl + sub*64;
  #pragma unroll 4
  for (int i=0;i<64;++i) acc2 = fmaf(fls[i], wscol[(size_t)i*NF], acc2);
  atomicAdd(&sk_pre[b*NF + colj], acc2);
}

// ---------------- pass2b: weight GRN + LN + softmax -> weights ----------------
__global__ __launch_bounds__(64) void k_pass2b(const float* __restrict__ hw_pre, const float* __restrict__ sk_pre,
    const float* __restrict__ B1, const float* __restrict__ W2, const float* __restrict__ B2,
    const float* __restrict__ Wg, const float* __restrict__ Bg, const float* __restrict__ Bs,
    const float* __restrict__ LNg, const float* __restrict__ LNb,
    float* __restrict__ out, float* __restrict__ wsel){
  __shared__ float hw[256];
  const int tid = threadIdx.x, b = blockIdx.x;
  for (int i=tid;i<256;i+=64) hw[i] = eluf(hw_pre[b*DM+i] + B1[i]);
  __syncthreads();
  if (tid < 32){
    const int j = tid;
    float ap = B2[j], ag = Bg[j];
    #pragma unroll 4
    for (int i=0;i<256;++i){ float h = hw[i]; ap = fmaf(h, W2[i*NF+j], ap); ag = fmaf(h, Wg[i*NF+j], ag); }
    float gw = sigm(ag);
    float v = sk_pre[b*NF+j] + Bs[j] + gw*ap;
    float s1 = v;
    s1 += __shfl_xor(s1,1); s1 += __shfl_xor(s1,2); s1 += __shfl_xor(s1,4); s1 += __shfl_xor(s1,8); s1 += __shfl_xor(s1,16);
    float mean = s1*(1.f/32.f);
    float dv = v - mean;
    float s2 = dv*dv;
    s2 += __shfl_xor(s2,1); s2 += __shfl_xor(s2,2); s2 += __shfl_xor(s2,4); s2 += __shfl_xor(s2,8); s2 += __shfl_xor(s2,16);
    float wn = fmaf(dv * rsqrtf(s2*(1.f/32.f) + EPS), LNg[j], LNb[j]);
    float mx = wn;
    mx = fmaxf(mx, __shfl_xor(mx,1)); mx = fmaxf(mx, __shfl_xor(mx,2)); mx = fmaxf(mx, __shfl_xor(mx,4));
    mx = fmaxf(mx, __shfl_xor(mx,8)); mx = fmaxf(mx, __shfl_xor(mx,16));
    float e = __expf(wn - mx);
    float se = e;
    se += __shfl_xor(se,1); se += __shfl_xor(se,2); se += __shfl_xor(se,4); se += __shfl_xor(se,8); se += __shfl_xor(se,16);
    float wgt = e / se;
    out[OUT_W_OFF + b*NF + j] = wgt;
    wsel[b*NF + j] = wgt;
  }
}

// ---------------- combine: out[t,d] = sum_f w[b,f] * shat[f,t,d] ----------------
// One token per wave; 16 independent uint4 loads per lane (f-half per 32-lane group).
__global__ __launch_bounds__(256) void k_comb(const uint4* __restrict__ stk4,
    const float* __restrict__ wsel, float* __restrict__ out){
  __shared__ float wloc[NF];
  const int tid = threadIdx.x, lane = tid&63;
  const int t = blockIdx.x*4 + (tid>>6);
  const int b = t >> 9;
  if (tid < NF) wloc[tid] = wsel[b*NF + tid];
  __syncthreads();
  const int oc = lane&31, fh = lane>>5;
  float acc[8];
  #pragma unroll
  for (int j=0;j<8;++j) acc[j]=0.f;
  #pragma unroll
  for (int j=0;j<16;++j){
    int f = fh*16 + j;
    uint4 v = stk4[(size_t)f*262144 + (size_t)t*32 + oc];
    f16x8 hv = __builtin_bit_cast(f16x8, v);
    float wf = wloc[f];
    #pragma unroll
    for (int jj=0;jj<8;++jj) acc[jj] = fmaf(wf, (float)hv[jj], acc[jj]);
  }
  #pragma unroll
  for (int jj=0;jj<8;++jj) acc[jj] += __shfl_xor(acc[jj], 32);
  if (fh == 0){
    float4* o = (float4*)(out + (size_t)t*DM + oc*8);
    o[0] = make_float4(acc[0],acc[1],acc[2],acc[3]);
    o[1] = make_float4(acc[4],acc[5],acc[6],acc[7]);
  }
}

extern "C" void kernel_launch(void* const* d_in, const int* in_sizes, int n_in,
                              void* d_out, int out_size, void* d_ws, size_t ws_size,
                              hipStream_t stream) {
  const float* x   = (const float*)d_in[0];
  const float* w1  = (const float*)d_in[1];
  const float* b1  = (const float*)d_in[2];
  const float* w2  = (const float*)d_in[3];
  const float* b2  = (const float*)d_in[4];
  const float* wgm = (const float*)d_in[5];
  const float* bg  = (const float*)d_in[6];
  const float* wsk = (const float*)d_in[7];
  const float* bsk = (const float*)d_in[8];
  const float* lng = (const float*)d_in[9];
  const float* lnb = (const float*)d_in[10];
  const float* W1  = (const float*)d_in[11];
  const float* B1  = (const float*)d_in[12];
  const float* W2  = (const float*)d_in[13];
  const float* B2  = (const float*)d_in[14];
  const float* Wg  = (const float*)d_in[15];
  const float* Bg  = (const float*)d_in[16];
  const float* Wsm = (const float*)d_in[17];
  const float* Bs  = (const float*)d_in[18];
  const float* LNg = (const float*)d_in[19];
  const float* LNb = (const float*)d_in[20];
  float* out = (float*)d_out;

  char* ws = (char*)d_ws;
  uint4* Wpk    = (uint4*)ws;                     // 4 MB bf16-packed weights
  uint4* stk4   = (uint4*)(ws + 4194304);         // 128 MiB fp16 shat [f][t][d]
  float* pooled = (float*)(ws + 138412032);       // 512 KB
  float* hw_pre = (float*)(ws + 138936320);       // 16 KB
  float* sk_pre = (float*)(ws + 138952704);       // 2 KB
  float* wsel   = (float*)(ws + 138954752);       // 2 KB

  (void)hipMemsetAsync(pooled, 0, 524288, stream);
  (void)hipMemsetAsync(hw_pre, 0, 16384 + 2048, stream);

  k_prep<<<dim3(32,8), 256, 0, stream>>>(w2, wgm, Wpk);
  k_pass1<<<dim3(64,32), 512, 0, stream>>>(x, w1, b1, b2, bg, wsk, bsk, lng, lnb,
                                           Wpk, pooled, stk4);
  k_pass2a<<<dim3(16,16), 256, 0, stream>>>(pooled, W1, Wsm, hw_pre, sk_pre);
  k_pass2b<<<16, 64, 0, stream>>>(hw_pre, sk_pre, B1, W2, B2, Wg, Bg, Bs, LNg, LNb, out, wsel);
  k_comb<<<2048, 256, 0, stream>>>(stk4, wsel, out);
}

// Round 6
// 295.436 us; speedup vs baseline: 1.3560x; 1.0243x over previous
//
#include <hip/hip_runtime.h>
#include <hip/hip_fp16.h>

// Problem constants
#define NF 32
#define DM 256
#define HH 128
#define BB 16
#define TT 512
#define BT 8192            // B*T tokens
#define OUT_W_OFF 2097152  // B*T*D
#define EPS 1e-5f

typedef __bf16 bf16x8 __attribute__((ext_vector_type(8)));
typedef float  f32x16 __attribute__((ext_vector_type(16)));
typedef __fp16 f16x2 __attribute__((ext_vector_type(2)));
typedef __fp16 f16x8 __attribute__((ext_vector_type(8)));

__device__ __forceinline__ float eluf(float z){ return z > 0.f ? z : __expf(z) - 1.f; }
__device__ __forceinline__ float sigm(float z){ return 1.f/(1.f + __expf(-z)); }
__device__ __forceinline__ unsigned f2bf(float x){
  unsigned u = __float_as_uint(x);
  u += 0x7fffu + ((u>>16)&1u);   // RNE
  return u>>16;
}

// Build A = elu(x*w1+b1) (MT*32 tokens x 128 k) in MFMA A-frag order, shared via LDS:
// Apack[mt][ks][lane][j] ; m=mt*32+(lane&31), k=ks*16+(lane>>5)*8+j
template<int MT, int NTHR>
__device__ __forceinline__ void build_A(uint4* Apack, const float* __restrict__ x,
                                        const float* __restrict__ w1, const float* __restrict__ b1,
                                        int f, int tok0, int tid){
  #pragma unroll
  for (int p = 0; p < (MT*512)/NTHR; ++p){
    int slot = tid + p*NTHR;
    int l  = slot & 63;
    int ks = (slot>>6)&7;
    int mt = slot>>9;
    int m  = mt*32 + (l&31);
    int k0 = ks*16 + (l>>5)*8;
    float xv = x[(tok0+m)*NF + f];
    const float* wp = w1 + f*HH + k0;
    const float* bp = b1 + f*HH + k0;
    float4 wa = *(const float4*)wp, wb = *(const float4*)(wp+4);
    float4 ba = *(const float4*)bp, bb = *(const float4*)(bp+4);
    bf16x8 v;
    v[0] = (__bf16)eluf(fmaf(xv, wa.x, ba.x));
    v[1] = (__bf16)eluf(fmaf(xv, wa.y, ba.y));
    v[2] = (__bf16)eluf(fmaf(xv, wa.z, ba.z));
    v[3] = (__bf16)eluf(fmaf(xv, wa.w, ba.w));
    v[4] = (__bf16)eluf(fmaf(xv, wb.x, bb.x));
    v[5] = (__bf16)eluf(fmaf(xv, wb.y, bb.y));
    v[6] = (__bf16)eluf(fmaf(xv, wb.z, bb.z));
    v[7] = (__bf16)eluf(fmaf(xv, wb.w, bb.w));
    Apack[slot] = __builtin_bit_cast(uint4, v);
  }
}

// ---------------- prep: repack w2/wg (f32) -> bf16 B-fragment layout ----------------
__global__ __launch_bounds__(256) void k_prep(const float* __restrict__ w2,
                                              const float* __restrict__ wgm,
                                              uint4* __restrict__ Wpk){
  __shared__ float ssrc[2][128][32];
  const int tid = threadIdx.x;
  const int f = blockIdx.x, c = blockIdx.y;
  #pragma unroll
  for (int it = 0; it < 32; ++it){
    int idx = tid + it*256;
    int arr = idx >> 12;
    int rem = idx & 4095;
    int k = rem >> 5, dd = rem & 31;
    const float* src = arr ? wgm : w2;
    ssrc[arr][k][dd] = src[(f*HH + k)*DM + c*32 + dd];
  }
  __syncthreads();
  #pragma unroll
  for (int p = 0; p < 4; ++p){
    int oc = tid + p*256;
    int nt = oc>>9, ks = (oc>>6)&7, l = oc&63;
    int k0 = ks*16 + (l>>5)*8, dd = l&31;
    float v[8];
    #pragma unroll
    for (int j=0;j<8;++j) v[j] = ssrc[nt][k0+j][dd];
    uint4 pk;
    pk.x = f2bf(v[0]) | (f2bf(v[1])<<16);
    pk.y = f2bf(v[2]) | (f2bf(v[3])<<16);
    pk.z = f2bf(v[4]) | (f2bf(v[5])<<16);
    pk.w = f2bf(v[6]) | (f2bf(v[7])<<16);
    Wpk[(f*8 + c)*1024 + oc] = pk;
  }
}

// ---------------- pass1: GRN + LN + store shat(fp16) + pooled sums ----------------
// 512 threads / 8 waves; 128 tokens. wave = (tt = wid>>1, ch = wid&1):
// 32 tokens x 4 c-chunks. VGPR 64 + 32 AGPR -> 128-class -> 4 waves/SIMD,
// 2 blocks/CU (LDS-bound) = 16 waves/CU (R4/R5-verified: occ ~40%).
// R6: stk4 layout is now token-major [t][f][d] (16 KB/token) so k_comb streams
// contiguously; pass1 writes 512B chunks at 16KB stride (still coalesced).
__global__ __launch_bounds__(512, 2) void k_pass1(const float* __restrict__ x,  const float* __restrict__ w1,
    const float* __restrict__ b1, const float* __restrict__ b2, const float* __restrict__ bg,
    const float* __restrict__ wsk, const float* __restrict__ bsk,
    const float* __restrict__ lng, const float* __restrict__ lnb,
    const uint4* __restrict__ Wpk,
    float* __restrict__ pooled, uint4* __restrict__ stk4){
  __shared__ uint4 smem[4096];          // 64 KB: Apack (first 2048 = 32 KB), then fp16 stage [128 t][256 d]
  __shared__ float xs[128];
  __shared__ float poolbuf[256];
  const int tid = threadIdx.x, lane = tid&63, wid = tid>>6;
  const int tt = wid>>1, ch = wid&1;    // token tile / d-half
  const int col = lane&31, q = lane>>5;
  const int f = blockIdx.y;
  const int tok0 = blockIdx.x*128;
  const int b = tok0 >> 9;
  if (tid < 256) poolbuf[tid] = 0.f;
  if (tid < 128) xs[tid] = x[(tok0 + tid)*NF + f];

  build_A<4,512>(smem, x, w1, b1, f, tok0, tid);
  __syncthreads();
  bf16x8 afr[8];
  #pragma unroll
  for (int ks=0; ks<8; ++ks) afr[ks] = __builtin_bit_cast(bf16x8, smem[(tt*8+ks)*64 + lane]);
  __syncthreads();   // all Apack reads done; stage writes may begin

  __fp16* stage = (__fp16*)smem;        // [128 t][256 d]
  #pragma unroll 1
  for (int ci=0; ci<4; ++ci){
    const int c = ch*4 + ci;
    const uint4* wb = Wpk + (f*8 + c)*1024;
    bf16x8 bfr[8];
    #pragma unroll
    for (int ks=0;ks<8;++ks) bfr[ks] = __builtin_bit_cast(bf16x8, wb[ks*64 + lane]);
    f32x16 acc0 = {0.f};
    #pragma unroll
    for (int ks=0;ks<8;++ks) acc0 = __builtin_amdgcn_mfma_f32_32x32x16_bf16(afr[ks], bfr[ks], acc0, 0,0,0);
    __builtin_amdgcn_sched_barrier(0);  // keep second B-batch from hoisting (reg pressure)
    #pragma unroll
    for (int ks=0;ks<8;++ks) bfr[ks] = __builtin_bit_cast(bf16x8, wb[512 + ks*64 + lane]);
    f32x16 acc1 = {0.f};
    #pragma unroll
    for (int ks=0;ks<8;++ks) acc1 = __builtin_amdgcn_mfma_f32_32x32x16_bf16(afr[ks], bfr[ks], acc1, 0,0,0);
    __builtin_amdgcn_sched_barrier(0);
    const int d = c*32 + col;
    const float b2v = b2[f*DM+d], bgv = bg[f*DM+d];
    #pragma unroll
    for (int i=0;i<8;++i){
      const int r0 = 2*i, r1 = r0+1;
      const int t0 = tt*32 + (r0&3) + 8*(i>>1) + 4*q;
      stage[ t0   *256 + d] = (__fp16)(sigm(acc1[r0]+bgv)*(acc0[r0]+b2v));
      stage[(t0+1)*256 + d] = (__fp16)(sigm(acc1[r1]+bgv)*(acc0[r1]+b2v));
    }
  }
  __syncthreads();   // stage + xs complete

  // --- dump: add skip, LN stats via 32-lane tree, apply LN, write + pool ---
  const int oc = tid & 31;          // d-octet, constant per thread
  float4 ga = *(const float4*)(lng + f*DM + oc*8);
  float4 gb = *(const float4*)(lng + f*DM + oc*8 + 4);
  float4 la = *(const float4*)(lnb + f*DM + oc*8);
  float4 lb = *(const float4*)(lnb + f*DM + oc*8 + 4);
  float4 wa = *(const float4*)(wsk + f*DM + oc*8);
  float4 wbv = *(const float4*)(wsk + f*DM + oc*8 + 4);
  float4 sa = *(const float4*)(bsk + f*DM + oc*8);
  float4 sb = *(const float4*)(bsk + f*DM + oc*8 + 4);
  float gj[8] = {ga.x,ga.y,ga.z,ga.w,gb.x,gb.y,gb.z,gb.w};
  float bj[8] = {la.x,la.y,la.z,la.w,lb.x,lb.y,lb.z,lb.w};
  float wj[8] = {wa.x,wa.y,wa.z,wa.w,wbv.x,wbv.y,wbv.z,wbv.w};
  float cj[8] = {sa.x,sa.y,sa.z,sa.w,sb.x,sb.y,sb.z,sb.w};
  float ps[8];
  #pragma unroll
  for (int j=0;j<8;++j) ps[j]=0.f;
  #pragma unroll
  for (int p=0;p<8;++p){
    int slot = tid + p*512;          // [t(128)][oc(32)]
    int t = slot >> 5;
    uint4 v = smem[slot];
    f16x8 s8 = __builtin_bit_cast(f16x8, v);
    float xt = xs[t];
    float s[8];
    float ssum = 0.f, ssq = 0.f;
    #pragma unroll
    for (int j=0;j<8;++j){
      s[j] = fmaf(xt, wj[j], cj[j]) + (float)s8[j];
      ssum += s[j];
      ssq = fmaf(s[j], s[j], ssq);
    }
    // token row t is fully owned by this 32-lane group
    ssum += __shfl_xor(ssum,1);  ssq += __shfl_xor(ssq,1);
    ssum += __shfl_xor(ssum,2);  ssq += __shfl_xor(ssq,2);
    ssum += __shfl_xor(ssum,4);  ssq += __shfl_xor(ssq,4);
    ssum += __shfl_xor(ssum,8);  ssq += __shfl_xor(ssq,8);
    ssum += __shfl_xor(ssum,16); ssq += __shfl_xor(ssq,16);
    float mu = ssum * (1.f/256.f);
    float var = fmaf(-mu, mu, ssq*(1.f/256.f));
    float rs = rsqrtf(fmaxf(var, 0.f) + EPS);
    float nmr = -mu*rs;
    float sh[8];
    #pragma unroll
    for (int j=0;j<8;++j){
      sh[j] = fmaf(fmaf(s[j], rs, nmr), gj[j], bj[j]);
      ps[j] += sh[j];
    }
    uint4 pk;
    pk.x = __builtin_bit_cast(unsigned, __builtin_amdgcn_cvt_pkrtz(sh[0], sh[1]));
    pk.y = __builtin_bit_cast(unsigned, __builtin_amdgcn_cvt_pkrtz(sh[2], sh[3]));
    pk.z = __builtin_bit_cast(unsigned, __builtin_amdgcn_cvt_pkrtz(sh[4], sh[5]));
    pk.w = __builtin_bit_cast(unsigned, __builtin_amdgcn_cvt_pkrtz(sh[6], sh[7]));
    // token-major layout: [t][f][d] -> 1024 uint4 per token
    stk4[(size_t)(tok0 + t)*1024 + (size_t)f*32 + oc] = pk;
  }
  // fold lane pairs (l, l+32) sharing oc, then one LDS atomic per cell
  #pragma unroll
  for (int j=0;j<8;++j) ps[j] += __shfl_xor(ps[j], 32);
  if (q == 0){
    #pragma unroll
    for (int j=0;j<8;++j) atomicAdd(&poolbuf[oc*8 + j], ps[j]);
  }
  __syncthreads();
  if (tid < 256) atomicAdd(&pooled[b*8192 + f*DM + tid], poolbuf[tid]);
}

// ---------------- pass2a: flat_pooled @ W1 / @ Ws (split-K partials) ----------------
__global__ __launch_bounds__(256) void k_pass2a(const float* __restrict__ pooled,
    const float* __restrict__ W1, const float* __restrict__ Wsm,
    float* __restrict__ hw_pre, float* __restrict__ sk_pre){
  __shared__ float fl[512];
  const int tid = threadIdx.x;
  const int b = blockIdx.x;
  const int k0 = blockIdx.y * 512;
  fl[tid]       = pooled[b*8192 + k0 + tid]       * (1.f/512.f);
  fl[tid+256]   = pooled[b*8192 + k0 + tid + 256] * (1.f/512.f);
  __syncthreads();
  float acc = 0.f;
  const float* wcol = W1 + (size_t)k0*DM + tid;
  #pragma unroll 4
  for (int i=0;i<512;++i) acc = fmaf(fl[i], wcol[(size_t)i*DM], acc);
  atomicAdd(&hw_pre[b*DM + tid], acc);
  const int colj = tid & 31, sub = tid >> 5;
  float acc2 = 0.f;
  const float* wscol = Wsm + (size_t)(k0 + sub*64)*NF + colj;
  const float* fls = fl + sub*64;
  #pragma unroll 4
  for (int i=0;i<64;++i) acc2 = fmaf(fls[i], wscol[(size_t)i*NF], acc2);
  atomicAdd(&sk_pre[b*NF + colj], acc2);
}

// ---------------- pass2b: weight GRN + LN + softmax -> weights ----------------
__global__ __launch_bounds__(64) void k_pass2b(const float* __restrict__ hw_pre, const float* __restrict__ sk_pre,
    const float* __restrict__ B1, const float* __restrict__ W2, const float* __restrict__ B2,
    const float* __restrict__ Wg, const float* __restrict__ Bg, const float* __restrict__ Bs,
    const float* __restrict__ LNg, const float* __restrict__ LNb,
    float* __restrict__ out, float* __restrict__ wsel){
  __shared__ float hw[256];
  const int tid = threadIdx.x, b = blockIdx.x;
  for (int i=tid;i<256;i+=64) hw[i] = eluf(hw_pre[b*DM+i] + B1[i]);
  __syncthreads();
  if (tid < 32){
    const int j = tid;
    float ap = B2[j], ag = Bg[j];
    #pragma unroll 4
    for (int i=0;i<256;++i){ float h = hw[i]; ap = fmaf(h, W2[i*NF+j], ap); ag = fmaf(h, Wg[i*NF+j], ag); }
    float gw = sigm(ag);
    float v = sk_pre[b*NF+j] + Bs[j] + gw*ap;
    float s1 = v;
    s1 += __shfl_xor(s1,1); s1 += __shfl_xor(s1,2); s1 += __shfl_xor(s1,4); s1 += __shfl_xor(s1,8); s1 += __shfl_xor(s1,16);
    float mean = s1*(1.f/32.f);
    float dv = v - mean;
    float s2 = dv*dv;
    s2 += __shfl_xor(s2,1); s2 += __shfl_xor(s2,2); s2 += __shfl_xor(s2,4); s2 += __shfl_xor(s2,8); s2 += __shfl_xor(s2,16);
    float wn = fmaf(dv * rsqrtf(s2*(1.f/32.f) + EPS), LNg[j], LNb[j]);
    float mx = wn;
    mx = fmaxf(mx, __shfl_xor(mx,1)); mx = fmaxf(mx, __shfl_xor(mx,2)); mx = fmaxf(mx, __shfl_xor(mx,4));
    mx = fmaxf(mx, __shfl_xor(mx,8)); mx = fmaxf(mx, __shfl_xor(mx,16));
    float e = __expf(wn - mx);
    float se = e;
    se += __shfl_xor(se,1); se += __shfl_xor(se,2); se += __shfl_xor(se,4); se += __shfl_xor(se,8); se += __shfl_xor(se,16);
    float wgt = e / se;
    out[OUT_W_OFF + b*NF + j] = wgt;
    wsel[b*NF + j] = wgt;
  }
}

// ---------------- combine: out[t,d] = sum_f w[b,f] * shat[t,f,d] ----------------
// Token-major stk4: each token is 16 KB contiguous; block of 4 tokens streams
// 64 KB sequentially (no multi-MiB strides -> no HBM channel aliasing).
__global__ __launch_bounds__(256) void k_comb(const uint4* __restrict__ stk4,
    const float* __restrict__ wsel, float* __restrict__ out){
  __shared__ float wloc[NF];
  const int tid = threadIdx.x, lane = tid&63;
  const int t = blockIdx.x*4 + (tid>>6);
  const int b = t >> 9;
  if (tid < NF) wloc[tid] = wsel[b*NF + tid];
  __syncthreads();
  const int oc = lane&31, fh = lane>>5;
  float acc[8];
  #pragma unroll
  for (int j=0;j<8;++j) acc[j]=0.f;
  #pragma unroll
  for (int j=0;j<16;++j){
    int f = fh*16 + j;
    uint4 v = stk4[(size_t)t*1024 + f*32 + oc];
    f16x8 hv = __builtin_bit_cast(f16x8, v);
    float wf = wloc[f];
    #pragma unroll
    for (int jj=0;jj<8;++jj) acc[jj] = fmaf(wf, (float)hv[jj], acc[jj]);
  }
  #pragma unroll
  for (int jj=0;jj<8;++jj) acc[jj] += __shfl_xor(acc[jj], 32);
  if (fh == 0){
    float4* o = (float4*)(out + (size_t)t*DM + oc*8);
    o[0] = make_float4(acc[0],acc[1],acc[2],acc[3]);
    o[1] = make_float4(acc[4],acc[5],acc[6],acc[7]);
  }
}

extern "C" void kernel_launch(void* const* d_in, const int* in_sizes, int n_in,
                              void* d_out, int out_size, void* d_ws, size_t ws_size,
                              hipStream_t stream) {
  const float* x   = (const float*)d_in[0];
  const float* w1  = (const float*)d_in[1];
  const float* b1  = (const float*)d_in[2];
  const float* w2  = (const float*)d_in[3];
  const float* b2  = (const float*)d_in[4];
  const float* wgm = (const float*)d_in[5];
  const float* bg  = (const float*)d_in[6];
  const float* wsk = (const float*)d_in[7];
  const float* bsk = (const float*)d_in[8];
  const float* lng = (const float*)d_in[9];
  const float* lnb = (const float*)d_in[10];
  const float* W1  = (const float*)d_in[11];
  const float* B1  = (const float*)d_in[12];
  const float* W2  = (const float*)d_in[13];
  const float* B2  = (const float*)d_in[14];
  const float* Wg  = (const float*)d_in[15];
  const float* Bg  = (const float*)d_in[16];
  const float* Wsm = (const float*)d_in[17];
  const float* Bs  = (const float*)d_in[18];
  const float* LNg = (const float*)d_in[19];
  const float* LNb = (const float*)d_in[20];
  float* out = (float*)d_out;

  char* ws = (char*)d_ws;
  uint4* Wpk    = (uint4*)ws;                     // 4 MB bf16-packed weights
  uint4* stk4   = (uint4*)(ws + 4194304);         // 128 MiB fp16 shat [t][f][d]
  float* pooled = (float*)(ws + 138412032);       // 512 KB
  float* hw_pre = (float*)(ws + 138936320);       // 16 KB
  float* sk_pre = (float*)(ws + 138952704);       // 2 KB
  float* wsel   = (float*)(ws + 138954752);       // 2 KB

  (void)hipMemsetAsync(pooled, 0, 524288, stream);
  (void)hipMemsetAsync(hw_pre, 0, 16384 + 2048, stream);

  k_prep<<<dim3(32,8), 256, 0, stream>>>(w2, wgm, Wpk);
  k_pass1<<<dim3(64,32), 512, 0, stream>>>(x, w1, b1, b2, bg, wsk, bsk, lng, lnb,
                                           Wpk, pooled, stk4);
  k_pass2a<<<dim3(16,16), 256, 0, stream>>>(pooled, W1, Wsm, hw_pre, sk_pre);
  k_pass2b<<<16, 64, 0, stream>>>(hw_pre, sk_pre, B1, W2, B2, Wg, Bg, Bs, LNg, LNb, out, wsel);
  k_comb<<<2048, 256, 0, stream>>>(stk4, wsel, out);
}